// Round 9
// baseline (398.826 us; speedup 1.0000x reference)
//
#include <hip/hip_runtime.h>

// LocallyConnectedLayer MI355X — R11: fragment-major B LDS + bg-merge.
//  - B LDS stored in MFMA-fragment order [jj][nt][s][lane][8]e: lane reads
//    bf16x8 at base+lane*16 -> stride-1, ZERO read bank conflicts (R10's
//    8.9M conflicts were these reads: 208B row stride = 8-way)
//  - bg-merge: 300 blocks x 512 thr (M=128, 8 waves): w read once per
//    (i,jg,og) -> w line traffic per output halved; occupancy 2x (LDS 73.7KB,
//    launch_bounds(512,4) -> 2 blocks/CU, 16 waves/CU)
//  - 16-lane coop w gather (e16<14; seg13 clamped to byte 200 = exact fit;
//    floats 50/51 double-written same value, benign)
//  - x path / funnel MFMA / epilogue = R8/R9/R10-proven
// out[b,o,i,j] = bias[o,i,j] + sum_{c,kh,kw} x[b,c,i+kh,j+kw]*W[c,o,i,j,kh,kw]

typedef __bf16 bf16x8 __attribute__((ext_vector_type(8)));
typedef float f32x4 __attribute__((ext_vector_type(4)));
typedef unsigned long long u64;
typedef unsigned int u32t;
typedef unsigned short u16t;

struct __attribute__((packed, aligned(8))) uf4 { f32x4 v; };
struct __attribute__((packed, aligned(4))) uf4a { f32x4 v; };  // 4B-aligned 16B
struct __attribute__((packed, aligned(8))) uf2 { float2 v; };
struct __attribute__((packed, aligned(4))) uq2 { u64 x, y; };  // 16B, 4-aligned
struct __attribute__((aligned(16))) ull2 { u64 x, y; };

__device__ __forceinline__ u16t f2bf(float f) {
  union { float f; u32t u; } v; v.f = f;
  u32t r = v.u + 0x7fffu + ((v.u >> 16) & 1u);  // RTNE
  return (u16t)(r >> 16);
}
__device__ __forceinline__ u32t pk2(float a, float b) {
  return (u32t)f2bf(a) | ((u32t)f2bf(b) << 16);
}
__device__ __forceinline__ bf16x8 mk_af(u64 lo, u64 hi) {
  union { u64 q[2]; bf16x8 v; } u;
  u.q[0] = lo; u.q[1] = hi;
  return u.v;
}

// x:    [128,64,32,32]  strides(f32) b:65536 c:1024 h:32 w:1
// Xb3:  [c 64][h 32][jg 5][b 128] x 16B (taps 6jg..6jg+7, bf16)  (20 MiB)
// Xb:   [c 64][h 32][b 128][w 32] bf16 (R9 tier)
// wgt:  [64(c),64(o),30,30,3,3]; (c,o) run of 54 floats at P*8100 + ij0*9
// bias: [64,30,30]; out: [128,64,30,30] strides b:57600 o:900 ij:1

// ============ prep (R10-proven): window-major ============
__global__ __launch_bounds__(256) void lcl_prep_x3(const float* __restrict__ x,
                                                   u16t* __restrict__ Xb) {
  int gid = blockIdx.x * 256 + threadIdx.x;  // (c*32+h)*128 + b
  int b  = gid & 127;
  int ch = gid >> 7;
  const float* src = x + (size_t)b * 65536 + ch * 32;  // 16B-aligned
  u64 qv[8];
#pragma unroll
  for (int s = 0; s < 8; ++s) {
    f32x4 a = ((const uf4*)(src + s * 4))->v;
    qv[s] = (u64)pk2(a[0], a[1]) | ((u64)pk2(a[2], a[3]) << 32);
  }
  u16t* dst = Xb + ((size_t)ch * 5 * 128 + b) * 8;  // +jg*1024 u16 per window
  ull2 w;
  w.x = qv[0];                          w.y = qv[1];                          *(ull2*)(dst)        = w;
  w.x = (qv[1] >> 32) | (qv[2] << 32);  w.y = (qv[2] >> 32) | (qv[3] << 32);  *(ull2*)(dst + 1024) = w;
  w.x = qv[3];                          w.y = qv[4];                          *(ull2*)(dst + 2048) = w;
  w.x = (qv[4] >> 32) | (qv[5] << 32);  w.y = (qv[5] >> 32) | (qv[6] << 32);  *(ull2*)(dst + 3072) = w;
  w.x = qv[6];                          w.y = qv[7];                          *(ull2*)(dst + 4096) = w;
}

// ============ main (R11) ============
__global__ __launch_bounds__(512, 4) void lcl_main11(
    const u16t* __restrict__ Xb, const float* __restrict__ wgt,
    const float* __restrict__ bias, float* __restrict__ out) {
  // 300 blocks -> XCD-contiguous bijective swizzle (300 = 4*38 + 4*37)
  int bid = blockIdx.x;
  int xcd = bid & 7, sg = bid >> 3;
  int t = (xcd < 4 ? xcd * 38 : 152 + (xcd - 4) * 37) + sg;
  int jg = t % 5;
  int r  = t / 5;                 // og + 2*i
  int og = r & 1, i = r >> 1;
  int j0 = jg * 6;
  int ij0 = i * 30 + j0;

  // B LDS fragment-major: [buf 2][jj 6][nt 2][s 3][lane 64][e 8] u16
  __shared__ __align__(16) u16t Bt[2 * 18432];  // 73728 B

  const int tid  = threadIdx.x;   // 0..511
  const int wave = tid >> 6;      // 0..7 (b-row group)
  const int lane = tid & 63;
  const int lrow = lane & 15;
  const int q    = lane >> 4;

  // zero-init (pads k'%4==3 i.e. e in {3,7} must stay 0); 9216 u64 = 512*18
  {
    u64* zp = (u64*)Bt;
#pragma unroll
    for (int k = 0; k < 18; ++k) zp[tid + k * 512] = 0ull;
  }

  // ---- A: window-major Xb3; one 16B aligned load per run
  const int b_x = wave * 16 + lrow;
  const char* xbase = (const char*)Xb;
  u32t xoff[3][2];
#pragma unroll
  for (int s = 0; s < 3; ++s)
#pragma unroll
    for (int tt = 0; tt < 2; ++tt) {
      int g = s * 8 + q * 2 + tt, cc = g / 3, kh = g - cc * 3;
      xoff[s][tt] = (u32t)((((cc * 32 + (i + kh)) * 5 + jg) * 128 + b_x) * 16);
    }

  // ---- W: 16-lane cooperative runs. e16 = seg, g16 = o-slot [0,32)
  const int e16 = tid & 15, g16 = tid >> 4 & 31;
  const bool wact = e16 < 14;
  const int e16b = (e16 * 16 > 200) ? 200 : e16 * 16;  // byte off in 216B run
  const int F0 = e16b >> 2;                            // first float index
  const int nt_o = g16 >> 4, lr_o = g16 & 15;
  int kk4_m[4], Bm_m[4];
#pragma unroll
  for (int m = 0; m < 4; ++m) {
    int F = F0 + m;             // < 54
    int dj = F / 9, rem = F - dj * 9;
    int kh = rem / 3, kw = rem - kh * 3;
    kk4_m[m] = kh * 4 + kw;
    Bm_m[m] = (dj * 6 + nt_o * 3) * 512 + lr_o * 8;
  }
  const char* wb = (const char*)(wgt + (size_t)(og * 32 + g16) * 8100 +
                                 ij0 * 9) + e16b;

  ull2  rq[3][2];     // A taps j0..j0+7 per run
  f32x4 wv8[8];       // w segs for p=0..7

#define LOAD_CHUNK11(C0)                                                    \
  {                                                                         \
    const size_t xadv = (size_t)(C0) * 327680;                              \
    _Pragma("unroll") for (int s = 0; s < 3; ++s)                           \
    _Pragma("unroll") for (int tt = 0; tt < 2; ++tt)                        \
      rq[s][tt] = *(const ull2*)(xbase + xadv + xoff[s][tt]);               \
    if (wact) {                                                             \
      _Pragma("unroll") for (int p = 0; p < 8; ++p)                         \
        wv8[p] = ((const uf4a*)(wb + (size_t)((C0) + p) * 2073600))->v;     \
    }                                                                       \
  }

  f32x4 acc[6][2];
#pragma unroll
  for (int a = 0; a < 6; ++a)
#pragma unroll
    for (int n = 0; n < 2; ++n) acc[a][n] = f32x4{0.f, 0.f, 0.f, 0.f};

  LOAD_CHUNK11(0)
  __syncthreads();   // zeros visible before first B data write

  for (int chunk = 0; chunk < 8; ++chunk) {
    u16t* Bb = Bt + (chunk & 1) * 18432;

    // ---- scatter w to fragment slots (32 ds_write_b16 per active thread)
    if (wact) {
#pragma unroll
      for (int p = 0; p < 8; ++p)
#pragma unroll
        for (int m = 0; m < 4; ++m) {
          int kp = p * 12 + kk4_m[m];                 // k' = p*12+kh*4+kw
          Bb[Bm_m[m] + ((kp >> 3) << 7) + (kp & 7)] = f2bf(wv8[p][m]);
        }
    }

    // ---- snapshot A taps (rq overwritten by next prefetch)
    u64 rb[3][2][2];
#pragma unroll
    for (int s = 0; s < 3; ++s)
#pragma unroll
      for (int tt = 0; tt < 2; ++tt) {
        rb[s][tt][0] = rq[s][tt].x;
        rb[s][tt][1] = rq[s][tt].y;
      }

    __syncthreads();

    // ---- issue next chunk's globals; latency hides under MFMA phase
    if (chunk < 7) LOAD_CHUNK11((chunk + 1) * 8)

    // ---- MFMA phase: A from regs (funnel), B from LDS (stride-1, no conflicts)
#pragma unroll
    for (int s = 0; s < 3; ++s) {
#pragma unroll
      for (int jj = 0; jj < 6; ++jj) {
        bf16x8 bfr0 = *(const bf16x8*)&Bb[((jj * 6 + 0 * 3 + s) << 9) + lane * 8];
        bf16x8 bfr1 = *(const bf16x8*)&Bb[((jj * 6 + 1 * 3 + s) << 9) + lane * 8];
        u64 lo, hi;
        if (jj == 0) {
          lo = rb[s][0][0];
          hi = rb[s][1][0];
        } else if (jj < 4) {
          lo = (rb[s][0][0] >> (16 * jj)) | (rb[s][0][1] << (64 - 16 * jj));
          hi = (rb[s][1][0] >> (16 * jj)) | (rb[s][1][1] << (64 - 16 * jj));
        } else if (jj == 4) {
          lo = rb[s][0][1];
          hi = rb[s][1][1];
        } else {
          lo = rb[s][0][1] >> 16;
          hi = rb[s][1][1] >> 16;
        }
        bf16x8 af = mk_af(lo, hi);
        acc[jj][0] = __builtin_amdgcn_mfma_f32_16x16x32_bf16(af, bfr0, acc[jj][0], 0, 0, 0);
        acc[jj][1] = __builtin_amdgcn_mfma_f32_16x16x32_bf16(af, bfr1, acc[jj][1], 0, 0, 0);
      }
    }
  }

  // ---- epilogue (R9-proven): D[row=q*4+rr][col=lrow]
  const int b0 = wave * 16 + q * 4;
#pragma unroll
  for (int nt = 0; nt < 2; ++nt) {
    int o = og * 32 + nt * 16 + lrow;
    const float* bp = bias + o * 900 + ij0;
    f32x4 b03 = ((const uf4*)bp)->v;
    float2 b45 = ((const uf2*)(bp + 4))->v;
#pragma unroll
    for (int rr = 0; rr < 4; ++rr) {
      float* op = out + (size_t)(b0 + rr) * 57600 + o * 900 + ij0;
      f32x4 r03;
      r03[0] = acc[0][nt][rr] + b03[0];
      r03[1] = acc[1][nt][rr] + b03[1];
      r03[2] = acc[2][nt][rr] + b03[2];
      r03[3] = acc[3][nt][rr] + b03[3];
      float2 r45;
      r45.x = acc[4][nt][rr] + b45.x;
      r45.y = acc[5][nt][rr] + b45.y;
      ((uf4*)op)->v = r03;
      ((uf2*)(op + 4))->v = r45;
    }
  }
}

// ============ prep (R9 tier, proven) ============
__global__ __launch_bounds__(256) void lcl_prep_x(const float* __restrict__ x,
                                                  u16t* __restrict__ Xb) {
  int gid = blockIdx.x * 256 + threadIdx.x;
  int b  = gid & 127;
  int ch = gid >> 7;
  const float* src = x + (size_t)b * 65536 + ch * 32;
  u16t* dst = Xb + (size_t)gid * 32;
  u64 qv[8];
#pragma unroll
  for (int s = 0; s < 8; ++s) {
    f32x4 a = ((const uf4*)(src + s * 4))->v;
    qv[s] = (u64)pk2(a[0], a[1]) | ((u64)pk2(a[2], a[3]) << 32);
  }
#pragma unroll
  for (int s = 0; s < 4; ++s) {
    ull2 w; w.x = qv[2 * s]; w.y = qv[2 * s + 1];
    *(ull2*)(dst + s * 8) = w;
  }
}

// ============ main (R9 tier, proven) ============
__global__ __launch_bounds__(256, 2) void lcl_main9(
    const u16t* __restrict__ Xb, const float* __restrict__ wgt,
    const float* __restrict__ bias, float* __restrict__ out) {
  int bid = blockIdx.x;
  int xcd = bid & 7, sg = bid >> 3;
  int t = xcd * 75 + sg;
  int jg = t % 5;
  int r  = t / 5;
  int bg = r & 1, og = (r >> 1) & 1, i = r >> 2;
  int j0 = jg * 6;
  int ij0 = i * 30 + j0;

  __shared__ __align__(16) u16t Bt[2 * 6 * 32 * 104];

  const int tid  = threadIdx.x;
  const int wave = tid >> 6;
  const int lane = tid & 63;
  const int lrow = lane & 15;
  const int q    = lane >> 4;

  {
    u64* zp = (u64*)Bt;
#pragma unroll
    for (int k = 0; k < 39; ++k) zp[tid + k * 256] = 0ull;
  }

  const int b_x = bg * 64 + wave * 16 + lrow;
  const char* xbase = (const char*)Xb;
  u32t xoff[3][2];
#pragma unroll
  for (int s = 0; s < 3; ++s)
#pragma unroll
    for (int tt = 0; tt < 2; ++tt) {
      int g = s * 8 + q * 2 + tt, cc = g / 3, kh = g - cc * 3;
      xoff[s][tt] = (u32t)(((cc * 32 + (i + kh)) * 128 + b_x) * 64 + j0 * 2);
    }

  const int e8 = tid & 7, g8 = tid >> 3;
  const int o_w = og * 32 + g8;
  const int FO0 = e8 * 4;
  const int FO1 = 22 + e8 * 4;
  int Pofs[8];
#pragma unroll
  for (int jm = 0; jm < 8; ++jm) {
    int F = ((jm & 4) ? FO1 : FO0) + (jm & 3);
    Pofs[jm] = (F / 9) * 3328 + ((F % 9) / 3) * 4 + (F % 3);
  }
  const float* wb = wgt + (size_t)o_w * 8100 + ij0 * 9;

  uq2   rq[3][2];
  f32x4 wreg[16];

#define LOAD_CHUNK9(C0)                                                     \
  {                                                                         \
    const size_t xadv = (size_t)(C0) * 262144;                              \
    _Pragma("unroll") for (int s = 0; s < 3; ++s)                           \
    _Pragma("unroll") for (int tt = 0; tt < 2; ++tt)                        \
      rq[s][tt] = *(const uq2*)(xbase + xadv + xoff[s][tt]);                \
    _Pragma("unroll") for (int k = 0; k < 16; ++k) {                        \
      const int p_ = k >> 1;                                                \
      const float* wq = wb + (size_t)((C0) + p_) * 518400 +                 \
                        ((k & 1) ? FO1 : FO0);                              \
      wreg[k] = ((const uf4a*)wq)->v;                                       \
    }                                                                       \
  }

  f32x4 acc[6][2];
#pragma unroll
  for (int a = 0; a < 6; ++a)
#pragma unroll
    for (int n = 0; n < 2; ++n) acc[a][n] = f32x4{0.f, 0.f, 0.f, 0.f};

  LOAD_CHUNK9(0)
  __syncthreads();

  for (int chunk = 0; chunk < 8; ++chunk) {
    u16t* Bb = Bt + (chunk & 1) * 19968 + g8 * 104;
#pragma unroll
    for (int k = 0; k < 16; ++k) {
      const int p_ = k >> 1, h_ = k & 1;
#pragma unroll
      for (int m = 0; m < 4; ++m)
        (Bb + Pofs[h_ * 4 + m])[p_ * 12] = f2bf(wreg[k][m]);
    }

    u64 rb[3][2][2];
#pragma unroll
    for (int s = 0; s < 3; ++s)
#pragma unroll
      for (int tt = 0; tt < 2; ++tt) {
        rb[s][tt][0] = rq[s][tt].x;
        rb[s][tt][1] = rq[s][tt].y;
      }

    __syncthreads();

    if (chunk < 7) LOAD_CHUNK9((chunk + 1) * 8)

#pragma unroll
    for (int s = 0; s < 3; ++s) {
#pragma unroll
      for (int jj = 0; jj < 6; ++jj) {
        bf16x8 bfr0 = *(const bf16x8*)&Bt[(chunk & 1) * 19968 + jj * 3328 +
                                          lrow * 104 + s * 32 + q * 8];
        bf16x8 bfr1 = *(const bf16x8*)&Bt[(chunk & 1) * 19968 + jj * 3328 +
                                          (16 + lrow) * 104 + s * 32 + q * 8];
        u64 lo, hi;
        if (jj == 0) {
          lo = rb[s][0][0];
          hi = rb[s][1][0];
        } else if (jj < 4) {
          lo = (rb[s][0][0] >> (16 * jj)) | (rb[s][0][1] << (64 - 16 * jj));
          hi = (rb[s][1][0] >> (16 * jj)) | (rb[s][1][1] << (64 - 16 * jj));
        } else if (jj == 4) {
          lo = rb[s][0][1];
          hi = rb[s][1][1];
        } else {
          lo = rb[s][0][1] >> 16;
          hi = rb[s][1][1] >> 16;
        }
        bf16x8 af = mk_af(lo, hi);
        acc[jj][0] = __builtin_amdgcn_mfma_f32_16x16x32_bf16(af, bfr0, acc[jj][0], 0, 0, 0);
        acc[jj][1] = __builtin_amdgcn_mfma_f32_16x16x32_bf16(af, bfr1, acc[jj][1], 0, 0, 0);
      }
    }
  }

  const int b0 = bg * 64 + wave * 16 + q * 4;
#pragma unroll
  for (int nt = 0; nt < 2; ++nt) {
    int o = og * 32 + nt * 16 + lrow;
    const float* bp = bias + o * 900 + ij0;
    f32x4 b03 = ((const uf4*)bp)->v;
    float2 b45 = ((const uf2*)(bp + 4))->v;
#pragma unroll
    for (int rr = 0; rr < 4; ++rr) {
      float* op = out + (size_t)(b0 + rr) * 57600 + o * 900 + ij0;
      f32x4 r03;
      r03[0] = acc[0][nt][rr] + b03[0];
      r03[1] = acc[1][nt][rr] + b03[1];
      r03[2] = acc[2][nt][rr] + b03[2];
      r03[3] = acc[3][nt][rr] + b03[3];
      float2 r45;
      r45.x = acc[4][nt][rr] + b45.x;
      r45.y = acc[5][nt][rr] + b45.y;
      ((uf4*)op)->v = r03;
      ((uf2*)(op + 4))->v = r45;
    }
  }
}

// ============ fallback: proven R4 kernel ============
__global__ __launch_bounds__(256, 2) void lcl_r4(
    const float* __restrict__ x, const float* __restrict__ wgt,
    const float* __restrict__ bias, float* __restrict__ out) {
  int blk = blockIdx.x;
  int xcd = blk & 7, sg = blk >> 3;
  int t = xcd * 56 + (xcd < 2 ? xcd : 2) + sg;
  int i = t / 15;
  int j0 = (t % 15) * 2;
  int ij0 = i * 30 + j0;

  __shared__ __align__(16) u16t Bt[2 * 2 * 64 * 104];

  const int tid  = threadIdx.x;
  const int wave = tid >> 6;
  const int lane = tid & 63;
  const int lrow = lane & 15;
  const int q    = lane >> 4;

  {
    u64* zp = (u64*)Bt;
#pragma unroll
    for (int k = 0; k < 26; ++k) zp[tid + k * 256] = 0ull;
  }

  int xoffF[3][2];
#pragma unroll
  for (int s = 0; s < 3; ++s)
#pragma unroll
    for (int tt = 0; tt < 2; ++tt) {
      int g = s * 8 + q * 2 + tt, cc = g / 3, kh = g - cc * 3;
      xoffF[s][tt] = cc * 1024 + kh * 32;
    }
  const float* xb0 = x + (wave * 32 + lrow) * 65536 + i * 32 + j0;
  const float* xb1 = xb0 + 16 * 65536;

  const int o_w = tid & 63;
  const float* wb0 = wgt + (size_t)wave * 518400 + o_w * 8100 + ij0 * 9;
  const float* wb1 = wb0 + (size_t)4 * 518400;

  f32x4 av[2][3][2];
  f32x4 wv[2][5];

#define LOAD_CHUNK4(C0)                                                       \
  {                                                                           \
    const float* xc0 = xb0 + (C0) * 1024;                                     \
    const float* xc1 = xb1 + (C0) * 1024;                                     \
    _Pragma("unroll") for (int s = 0; s < 3; ++s)                             \
    _Pragma("unroll") for (int tt = 0; tt < 2; ++tt) {                        \
      av[0][s][tt] = ((const uf4*)(xc0 + xoffF[s][tt]))->v;                   \
      av[1][s][tt] = ((const uf4*)(xc1 + xoffF[s][tt]))->v;                   \
    }                                                                         \
    const float* w0 = wb0 + (size_t)(C0) * 518400;                            \
    const float* w1 = wb1 + (size_t)(C0) * 518400;                            \
    _Pragma("unroll") for (int e = 0; e < 4; ++e) {                           \
      wv[0][e] = ((const uf4*)(w0 + e * 4))->v;                               \
      wv[1][e] = ((const uf4*)(w1 + e * 4))->v;                               \
    }                                                                         \
    wv[0][4] = ((const uf4*)(w0 + 14))->v;                                    \
    wv[1][4] = ((const uf4*)(w1 + 14))->v;                                    \
  }

  f32x4 acc[2][2][4];
#pragma unroll
  for (int a = 0; a < 2; ++a)
#pragma unroll
    for (int b = 0; b < 2; ++b)
#pragma unroll
      for (int c = 0; c < 4; ++c) acc[a][b][c] = f32x4{0.f, 0.f, 0.f, 0.f};

  LOAD_CHUNK4(0)

  for (int chunk = 0; chunk < 8; ++chunk) {
    u16t* B = Bt + (chunk & 1) * 13312;
#pragma unroll
    for (int p = 0; p < 2; ++p) {
      int ccl = wave + 4 * p;
      u16t* Bp = B + o_w * 104 + ccl * 12;
      *(u32t*)&Bp[0] = pk2(wv[p][0][0], wv[p][0][1]);
      Bp[2]  = f2bf(wv[p][0][2]);
      Bp[4]  = f2bf(wv[p][0][3]);
      Bp[5]  = f2bf(wv[p][1][0]);
      Bp[6]  = f2bf(wv[p][1][1]);
      *(u32t*)&Bp[8] = pk2(wv[p][1][2], wv[p][1][3]);
      Bp[10] = f2bf(wv[p][2][0]);
      u16t* Bq = Bp + 6656;
      *(u32t*)&Bq[0] = pk2(wv[p][2][1], wv[p][2][2]);
      Bq[2]  = f2bf(wv[p][2][3]);
      Bq[4]  = f2bf(wv[p][3][0]);
      Bq[5]  = f2bf(wv[p][3][1]);
      Bq[6]  = f2bf(wv[p][3][2]);
      *(u32t*)&Bq[8] = pk2(wv[p][3][3], wv[p][4][2]);
      Bq[10] = f2bf(wv[p][4][3]);
    }

    u64 rb[2][3][2];
#pragma unroll
    for (int mt = 0; mt < 2; ++mt)
#pragma unroll
      for (int s = 0; s < 3; ++s)
#pragma unroll
        for (int tt = 0; tt < 2; ++tt) {
          const f32x4 vv = av[mt][s][tt];
          rb[mt][s][tt] = (u64)pk2(vv[0], vv[1]) | ((u64)pk2(vv[2], vv[3]) << 32);
        }

    __syncthreads();

    if (chunk < 7) LOAD_CHUNK4((chunk + 1) * 8)

#pragma unroll
    for (int s = 0; s < 3; ++s) {
      bf16x8 bfr[2][4];
#pragma unroll
      for (int jj = 0; jj < 2; ++jj)
#pragma unroll
        for (int nt = 0; nt < 4; ++nt)
          bfr[jj][nt] = *reinterpret_cast<const bf16x8*>(
              &B[jj * 6656 + (nt * 16 + lrow) * 104 + s * 32 + q * 8]);
#pragma unroll
      for (int mt = 0; mt < 2; ++mt)
#pragma unroll
        for (int jj = 0; jj < 2; ++jj) {
          u64 lo = rb[mt][s][0] >> (jj * 16);
          u64 hi = rb[mt][s][1] >> (jj * 16);
          bf16x8 af = mk_af(lo, hi);
#pragma unroll
          for (int nt = 0; nt < 4; ++nt)
            acc[mt][jj][nt] = __builtin_amdgcn_mfma_f32_16x16x32_bf16(
                af, bfr[jj][nt], acc[mt][jj][nt], 0, 0, 0);
        }
    }
  }

#pragma unroll
  for (int nt = 0; nt < 4; ++nt) {
    int o = nt * 16 + lrow;
    float2 bv = *(const float2*)(bias + o * 900 + ij0);
#pragma unroll
    for (int mt = 0; mt < 2; ++mt) {
#pragma unroll
      for (int rr = 0; rr < 4; ++rr) {
        int b = wave * 32 + mt * 16 + q * 4 + rr;
        float2 res;
        res.x = acc[mt][0][nt][rr] + bv.x;
        res.y = acc[mt][1][nt][rr] + bv.y;
        *(float2*)(out + b * 57600 + o * 900 + ij0) = res;
      }
    }
  }
}

extern "C" void kernel_launch(void* const* d_in, const int* in_sizes, int n_in,
                              void* d_out, int out_size, void* d_ws,
                              size_t ws_size, hipStream_t stream) {
  const float* x    = (const float*)d_in[0];
  const float* wgt  = (const float*)d_in[1];
  const float* bias = (const float*)d_in[2];
  float* out        = (float*)d_out;
  if (ws_size >= (size_t)20971520 && d_ws != nullptr) {
    lcl_prep_x3<<<dim3(1024), dim3(256), 0, stream>>>(x, (u16t*)d_ws);
    lcl_main11<<<dim3(300), dim3(512), 0, stream>>>((const u16t*)d_ws, wgt, bias, out);
  } else if (ws_size >= (size_t)16777216 && d_ws != nullptr) {
    lcl_prep_x<<<dim3(1024), dim3(256), 0, stream>>>(x, (u16t*)d_ws);
    lcl_main9<<<dim3(600), dim3(256), 0, stream>>>((const u16t*)d_ws, wgt, bias, out);
  } else {
    lcl_r4<<<dim3(450), dim3(256), 0, stream>>>(x, wgt, bias, out);
  }
}